// Round 1
// baseline (434.222 us; speedup 1.0000x reference)
//
#include <hip/hip_runtime.h>
#include <hip/hip_bf16.h>
#include <stdint.h>

// Problem: out[b,i] = sum_j a_ext[b,j] * W[hash_idx[i,j]]
//   B=4096, FAN_IN=4096 (+1 bias col), FAN_OUT=4096, K-table=65536
// Strategy: materialize bf16 A_ext [B][KP] and Wv [FAN_OUT][KP] (K padded
// 4097->4160 with zeros), then m97-style bf16 MFMA GEMM-BT into fp32 C.

#define B_DIM   4096
#define FAN_IN  4096
#define FAN_OUT 4096
#define KD      (FAN_IN + 1)   // 4097
#define KP      4160           // padded to multiple of 64 (130 * BK)

#define BM 128
#define BN 128
#define BK 32

typedef __attribute__((ext_vector_type(8))) short  short8;   // 8 bf16 = 4 VGPRs
typedef __attribute__((ext_vector_type(4))) float  floatx4;  // MFMA acc

__device__ __forceinline__ unsigned short f2bf(float f) {
  union { float f; unsigned u; } v; v.f = f;
  unsigned u = v.u;
  u += 0x7fffu + ((u >> 16) & 1u);   // round-to-nearest-even
  return (unsigned short)(u >> 16);
}

__device__ __forceinline__ void async16(const void* g, void* l) {
  // direct global->LDS DMA, 16B/lane; LDS dest = wave-uniform base + lane*16
  __builtin_amdgcn_global_load_lds(
      (const __attribute__((address_space(1))) void*)g,
      (__attribute__((address_space(3))) void*)l, 16, 0, 0);
}

// ---- Kernel 1: A_ext[b][j] = bf16(a[b][j]); col 4096 = 1.0; cols 4097..KP-1 = 0
__global__ __launch_bounds__(256) void build_aext(
    const float* __restrict__ a, unsigned short* __restrict__ Ae) {
  const int row = blockIdx.x;
  const float* ar = a + (size_t)row * FAN_IN;
  unsigned short* er = Ae + (size_t)row * KP;
  for (int j4 = threadIdx.x; j4 < KP / 4; j4 += 256) {
    const int j = j4 * 4;
    float x0, x1, x2, x3;
    if (j + 3 < FAN_IN) {
      const float4 v = *(const float4*)(ar + j);   // 16B-aligned (row stride 16KB)
      x0 = v.x; x1 = v.y; x2 = v.z; x3 = v.w;
    } else {
      x0 = (j + 0 < FAN_IN) ? ar[j + 0] : ((j + 0 == FAN_IN) ? 1.0f : 0.0f);
      x1 = (j + 1 < FAN_IN) ? ar[j + 1] : ((j + 1 == FAN_IN) ? 1.0f : 0.0f);
      x2 = (j + 2 < FAN_IN) ? ar[j + 2] : ((j + 2 == FAN_IN) ? 1.0f : 0.0f);
      x3 = (j + 3 < FAN_IN) ? ar[j + 3] : ((j + 3 == FAN_IN) ? 1.0f : 0.0f);
    }
    ushort4 o;
    o.x = f2bf(x0); o.y = f2bf(x1); o.z = f2bf(x2); o.w = f2bf(x3);
    *(ushort4*)(er + j) = o;   // 8B store, aligned (row stride 8320B, j mult of 4)
  }
}

// ---- Kernel 2: Wv[i][j] = bf16(W[hash_idx[i][j]]) for j<4097; 0 for pad cols
__global__ __launch_bounds__(256) void build_wv(
    const int* __restrict__ hidx, const float* __restrict__ W,
    unsigned short* __restrict__ Wv) {
  const int row = blockIdx.x;
  const int* hr = hidx + (size_t)row * KD;
  unsigned short* wr = Wv + (size_t)row * KP;
  for (int j2 = threadIdx.x; j2 < KP / 2; j2 += 256) {
    const int j = j2 * 2;
    unsigned short o0 = 0, o1 = 0;
    if (j     < KD) o0 = f2bf(W[hr[j]]);       // W is 256KB -> L2-resident gather
    if (j + 1 < KD) o1 = f2bf(W[hr[j + 1]]);
    *(unsigned int*)(wr + j) = (unsigned int)o0 | ((unsigned int)o1 << 16);
  }
}

// ---- Kernel 3: C[M][N] = A[M][KP] * Bm[N][KP]^T  (bf16 in, fp32 out)
// 128x128 block tile, BK=32, 4 waves in 2x2, each wave 64x64 = 4x4 MFMA tiles.
__global__ __launch_bounds__(256) void gemm_bt(
    const unsigned short* __restrict__ A, const unsigned short* __restrict__ Bm,
    float* __restrict__ C, int M, int N) {
  __shared__ __align__(16) unsigned short As[BM * BK];   // 8 KB, row-major [128][32]
  __shared__ __align__(16) unsigned short Bs[BN * BK];   // 8 KB

  const int tid  = threadIdx.x;
  const int lane = tid & 63;
  const int wave = tid >> 6;
  const int bm = blockIdx.y * BM;
  const int bn = blockIdx.x * BN;
  const int wm = (wave >> 1) * 64;
  const int wn = (wave & 1) * 64;
  const int q  = lane >> 4;        // k-quad for MFMA operand layout
  const int r  = lane & 15;        // m/n index within 16
  const int srow = lane >> 2;      // staging: 16 rows per wave-load
  const int scol = (lane & 3) * 8; // staging: 8 bf16 (16B) per lane

  floatx4 acc[4][4] = {};

  for (int k0 = 0; k0 < KP; k0 += BK) {
    // stage: each wave DMAs 2x16 rows of A and of B (64B/row = 4 lanes/row)
#pragma unroll
    for (int l = 0; l < 2; l++) {
      const int trow = wave * 32 + l * 16;
      async16(A  + (size_t)(bm + trow + srow) * KP + k0 + scol, &As[trow * BK]);
      async16(Bm + (size_t)(bn + trow + srow) * KP + k0 + scol, &Bs[trow * BK]);
    }
    __syncthreads();   // emits s_waitcnt vmcnt(0) -> DMA complete for all waves

    short8 af[4], bf[4];
#pragma unroll
    for (int t = 0; t < 4; t++) {
      // A-operand layout: A[m = lane&15][k = q*8 + j]  (16B contiguous -> ds_read_b128)
      af[t] = *(const short8*)&As[(wm + t * 16 + r) * BK + q * 8];
      bf[t] = *(const short8*)&Bs[(wn + t * 16 + r) * BK + q * 8];
    }
#pragma unroll
    for (int mt = 0; mt < 4; mt++)
#pragma unroll
      for (int nt = 0; nt < 4; nt++)
        acc[mt][nt] = __builtin_amdgcn_mfma_f32_16x16x32_bf16(
            af[mt], bf[nt], acc[mt][nt], 0, 0, 0);
    __syncthreads();   // protect LDS from next iteration's staging
  }

  // C/D layout (verified m89/m91): col = lane&15, row = q*4 + reg
#pragma unroll
  for (int mt = 0; mt < 4; mt++)
#pragma unroll
    for (int nt = 0; nt < 4; nt++) {
      const int row0 = bm + wm + mt * 16 + q * 4;
      const int col  = bn + wn + nt * 16 + r;
#pragma unroll
      for (int i = 0; i < 4; i++)
        C[(size_t)(row0 + i) * N + col] = acc[mt][nt][i];
    }
}

extern "C" void kernel_launch(void* const* d_in, const int* in_sizes, int n_in,
                              void* d_out, int out_size, void* d_ws, size_t ws_size,
                              hipStream_t stream) {
  const float* a    = (const float*)d_in[0];   // [4096, 4096] fp32
  const int*   hidx = (const int*)d_in[1];     // [4096, 4097] int32
  const float* W    = (const float*)d_in[2];   // [65536] fp32
  float*       out  = (float*)d_out;           // [4096, 4096] fp32

  // workspace layout: A_ext bf16 [B_DIM][KP] | Wv bf16 [FAN_OUT][KP]  (68.2 MB)
  unsigned short* Ae = (unsigned short*)d_ws;
  unsigned short* Wv = Ae + (size_t)B_DIM * KP;

  build_aext<<<B_DIM, 256, 0, stream>>>(a, Ae);
  build_wv<<<FAN_OUT, 256, 0, stream>>>(hidx, W, Wv);
  gemm_bt<<<dim3(FAN_OUT / BN, B_DIM / BM), 256, 0, stream>>>(Ae, Wv, out, B_DIM, FAN_OUT);
}

// Round 2
// 375.634 us; speedup vs baseline: 1.1560x; 1.1560x over previous
//
#include <hip/hip_runtime.h>
#include <hip/hip_bf16.h>
#include <stdint.h>

// Problem: out[b,i] = sum_j a_ext[b,j] * W[hash_idx[i,j]]
//   B=4096, FAN_IN=4096 (+1 bias col), FAN_OUT=4096, K-table=65536
// Strategy: materialize bf16 A_ext [B][KP] and Wv [FAN_OUT][KP] (K padded
// 4097->4160 with zeros), then m97-style bf16 MFMA GEMM-BT into fp32 C.
// R2: build_wv rewritten as LDS-resident two-phase gather (W-bf16 half-table
// in 64KB LDS; indices held in registers across phases).

#define B_DIM   4096
#define FAN_IN  4096
#define FAN_OUT 4096
#define KD      (FAN_IN + 1)   // 4097
#define KP      4160           // padded to multiple of 64 (130 * BK)

#define BM 128
#define BN 128
#define BK 32

typedef __attribute__((ext_vector_type(8))) short  short8;   // 8 bf16 = 4 VGPRs
typedef __attribute__((ext_vector_type(4))) float  floatx4;  // MFMA acc

__device__ __forceinline__ unsigned short f2bf(float f) {
  union { float f; unsigned u; } v; v.f = f;
  unsigned u = v.u;
  u += 0x7fffu + ((u >> 16) & 1u);   // round-to-nearest-even
  return (unsigned short)(u >> 16);
}

__device__ __forceinline__ void async16(const void* g, void* l) {
  // direct global->LDS DMA, 16B/lane; LDS dest = wave-uniform base + lane*16
  __builtin_amdgcn_global_load_lds(
      (const __attribute__((address_space(1))) void*)g,
      (__attribute__((address_space(3))) void*)l, 16, 0, 0);
}

// ---- Kernel 1: A_ext[b][j] = bf16(a[b][j]); col 4096 = 1.0; cols 4097..KP-1 = 0
__global__ __launch_bounds__(256) void build_aext(
    const float* __restrict__ a, unsigned short* __restrict__ Ae) {
  const int row = blockIdx.x;
  const float* ar = a + (size_t)row * FAN_IN;
  unsigned short* er = Ae + (size_t)row * KP;
  for (int j4 = threadIdx.x; j4 < KP / 4; j4 += 256) {
    const int j = j4 * 4;
    float x0, x1, x2, x3;
    if (j + 3 < FAN_IN) {
      const float4 v = *(const float4*)(ar + j);   // 16B-aligned (row stride 16KB)
      x0 = v.x; x1 = v.y; x2 = v.z; x3 = v.w;
    } else {
      x0 = (j + 0 < FAN_IN) ? ar[j + 0] : ((j + 0 == FAN_IN) ? 1.0f : 0.0f);
      x1 = (j + 1 < FAN_IN) ? ar[j + 1] : ((j + 1 == FAN_IN) ? 1.0f : 0.0f);
      x2 = (j + 2 < FAN_IN) ? ar[j + 2] : ((j + 2 == FAN_IN) ? 1.0f : 0.0f);
      x3 = (j + 3 < FAN_IN) ? ar[j + 3] : ((j + 3 == FAN_IN) ? 1.0f : 0.0f);
    }
    ushort4 o;
    o.x = f2bf(x0); o.y = f2bf(x1); o.z = f2bf(x2); o.w = f2bf(x3);
    *(ushort4*)(er + j) = o;   // 8B store, aligned (row stride 8320B, j mult of 4)
  }
}

// ---- Kernel 2 (R2): Wv[i][j] = bf16(W[hash_idx[i][j]]) via LDS-resident table.
// 1024 blocks x 512 threads; block handles 4 rows. Two phases: LDS holds
// bf16(W[h*32768 .. h*32768+32768)) (64 KB); indices live in registers.
__global__ __launch_bounds__(512) void build_wv(
    const int* __restrict__ hidx, const float* __restrict__ W,
    unsigned short* __restrict__ Wv) {
  __shared__ unsigned short wl[32768];   // 64 KB: half of W as bf16
  const int t  = threadIdx.x;
  const int r0 = blockIdx.x * 4;

  // Load this block's indices into registers (fully coalesced: 4B/lane-consecutive)
  int          idx[4][9];
  unsigned short res[4][9];
#pragma unroll
  for (int row = 0; row < 4; row++) {
    const int* hr = hidx + (size_t)(r0 + row) * KD;
#pragma unroll
    for (int i = 0; i < 9; i++) {
      const int j = i * 512 + t;
      idx[row][i] = (j < KD) ? hr[j] : 0;
      res[row][i] = 0;
    }
  }

  for (int h = 0; h < 2; h++) {
    __syncthreads();   // protect phase-0 reads before phase-1 refill
    // Fill LDS: 32768 floats -> bf16. float4 loads, ushort4 (8B) LDS writes
    // (lane byte-stride 8 -> 2-way bank alias, free per m136).
    const float4* Wb = (const float4*)(W + h * 32768);
#pragma unroll
    for (int i = 0; i < 16; i++) {
      const int f4 = i * 512 + t;
      const float4 v = Wb[f4];
      ushort4 o;
      o.x = f2bf(v.x); o.y = f2bf(v.y); o.z = f2bf(v.z); o.w = f2bf(v.w);
      *(ushort4*)&wl[f4 * 4] = o;
    }
    __syncthreads();
    const int lo = h << 15;
#pragma unroll
    for (int row = 0; row < 4; row++)
#pragma unroll
      for (int i = 0; i < 9; i++) {
        const int v = idx[row][i];
        if ((v & 32768) == lo)            // index falls in resident half
          res[row][i] = wl[v & 32767];    // random ds_read_u16
      }
  }

  // Store results + zero the KD..KP-1 pad columns
#pragma unroll
  for (int row = 0; row < 4; row++) {
    unsigned short* wr = Wv + (size_t)(r0 + row) * KP;
#pragma unroll
    for (int i = 0; i < 9; i++) {
      const int j = i * 512 + t;
      if (j < KD) wr[j] = res[row][i];
    }
    if (t < KP - KD) wr[KD + t] = 0;
  }
}

// ---- Kernel 3: C[M][N] = A[M][KP] * Bm[N][KP]^T  (bf16 in, fp32 out)
// 128x128 block tile, BK=32, 4 waves in 2x2, each wave 64x64 = 4x4 MFMA tiles.
__global__ __launch_bounds__(256) void gemm_bt(
    const unsigned short* __restrict__ A, const unsigned short* __restrict__ Bm,
    float* __restrict__ C, int M, int N) {
  __shared__ __align__(16) unsigned short As[BM * BK];   // 8 KB, row-major [128][32]
  __shared__ __align__(16) unsigned short Bs[BN * BK];   // 8 KB

  const int tid  = threadIdx.x;
  const int lane = tid & 63;
  const int wave = tid >> 6;
  const int bm = blockIdx.y * BM;
  const int bn = blockIdx.x * BN;
  const int wm = (wave >> 1) * 64;
  const int wn = (wave & 1) * 64;
  const int q  = lane >> 4;        // k-quad for MFMA operand layout
  const int r  = lane & 15;        // m/n index within 16
  const int srow = lane >> 2;      // staging: 16 rows per wave-load
  const int scol = (lane & 3) * 8; // staging: 8 bf16 (16B) per lane

  floatx4 acc[4][4] = {};

  for (int k0 = 0; k0 < KP; k0 += BK) {
    // stage: each wave DMAs 2x16 rows of A and of B (64B/row = 4 lanes/row)
#pragma unroll
    for (int l = 0; l < 2; l++) {
      const int trow = wave * 32 + l * 16;
      async16(A  + (size_t)(bm + trow + srow) * KP + k0 + scol, &As[trow * BK]);
      async16(Bm + (size_t)(bn + trow + srow) * KP + k0 + scol, &Bs[trow * BK]);
    }
    __syncthreads();   // emits s_waitcnt vmcnt(0) -> DMA complete for all waves

    short8 af[4], bf[4];
#pragma unroll
    for (int t = 0; t < 4; t++) {
      // A-operand layout: A[m = lane&15][k = q*8 + j]  (16B contiguous -> ds_read_b128)
      af[t] = *(const short8*)&As[(wm + t * 16 + r) * BK + q * 8];
      bf[t] = *(const short8*)&Bs[(wn + t * 16 + r) * BK + q * 8];
    }
#pragma unroll
    for (int mt = 0; mt < 4; mt++)
#pragma unroll
      for (int nt = 0; nt < 4; nt++)
        acc[mt][nt] = __builtin_amdgcn_mfma_f32_16x16x32_bf16(
            af[mt], bf[nt], acc[mt][nt], 0, 0, 0);
    __syncthreads();   // protect LDS from next iteration's staging
  }

  // C/D layout (verified m89/m91): col = lane&15, row = q*4 + reg
#pragma unroll
  for (int mt = 0; mt < 4; mt++)
#pragma unroll
    for (int nt = 0; nt < 4; nt++) {
      const int row0 = bm + wm + mt * 16 + q * 4;
      const int col  = bn + wn + nt * 16 + r;
#pragma unroll
      for (int i = 0; i < 4; i++)
        C[(size_t)(row0 + i) * N + col] = acc[mt][nt][i];
    }
}

extern "C" void kernel_launch(void* const* d_in, const int* in_sizes, int n_in,
                              void* d_out, int out_size, void* d_ws, size_t ws_size,
                              hipStream_t stream) {
  const float* a    = (const float*)d_in[0];   // [4096, 4096] fp32
  const int*   hidx = (const int*)d_in[1];     // [4096, 4097] int32
  const float* W    = (const float*)d_in[2];   // [65536] fp32
  float*       out  = (float*)d_out;           // [4096, 4096] fp32

  // workspace layout: A_ext bf16 [B_DIM][KP] | Wv bf16 [FAN_OUT][KP]  (68.2 MB)
  unsigned short* Ae = (unsigned short*)d_ws;
  unsigned short* Wv = Ae + (size_t)B_DIM * KP;

  build_aext<<<B_DIM, 256, 0, stream>>>(a, Ae);
  build_wv<<<FAN_OUT / 4, 512, 0, stream>>>(hidx, W, Wv);
  gemm_bt<<<dim3(FAN_OUT / BN, B_DIM / BM), 256, 0, stream>>>(Ae, Wv, out, B_DIM, FAN_OUT);
}

// Round 3
// 375.342 us; speedup vs baseline: 1.1569x; 1.0008x over previous
//
#include <hip/hip_runtime.h>
#include <hip/hip_bf16.h>
#include <stdint.h>

// Problem: out[b,i] = sum_j a_ext[b,j] * W[hash_idx[i,j]]
//   B=4096, FAN_IN=4096 (+1 bias col), FAN_OUT=4096, K-table=65536
// Strategy: materialize bf16 A_ext [B][KP] and Wv [FAN_OUT][KP] (K padded
// 4097->4160 with zeros), then m97-style bf16 MFMA GEMM-BT into fp32 C.
// R2: build_wv = LDS-resident two-phase gather (64KB half-table in LDS).
// R3: gemm BK 32->64 (32 MFMA per barrier, halves the vmcnt(0) barrier-drain
//     count; LDS 32KB keeps occupancy at the VGPR-capped ~3 blocks/CU).

#define B_DIM   4096
#define FAN_IN  4096
#define FAN_OUT 4096
#define KD      (FAN_IN + 1)   // 4097
#define KP      4160           // padded to multiple of 64 (65 * BK)

#define BM 128
#define BN 128
#define BK 64

typedef __attribute__((ext_vector_type(8))) short  short8;   // 8 bf16 = 4 VGPRs
typedef __attribute__((ext_vector_type(4))) float  floatx4;  // MFMA acc

__device__ __forceinline__ unsigned short f2bf(float f) {
  union { float f; unsigned u; } v; v.f = f;
  unsigned u = v.u;
  u += 0x7fffu + ((u >> 16) & 1u);   // round-to-nearest-even
  return (unsigned short)(u >> 16);
}

__device__ __forceinline__ void async16(const void* g, void* l) {
  // direct global->LDS DMA, 16B/lane; LDS dest = wave-uniform base + lane*16
  __builtin_amdgcn_global_load_lds(
      (const __attribute__((address_space(1))) void*)g,
      (__attribute__((address_space(3))) void*)l, 16, 0, 0);
}

// ---- Kernel 1: A_ext[b][j] = bf16(a[b][j]); col 4096 = 1.0; cols 4097..KP-1 = 0
__global__ __launch_bounds__(256) void build_aext(
    const float* __restrict__ a, unsigned short* __restrict__ Ae) {
  const int row = blockIdx.x;
  const float* ar = a + (size_t)row * FAN_IN;
  unsigned short* er = Ae + (size_t)row * KP;
  for (int j4 = threadIdx.x; j4 < KP / 4; j4 += 256) {
    const int j = j4 * 4;
    float x0, x1, x2, x3;
    if (j + 3 < FAN_IN) {
      const float4 v = *(const float4*)(ar + j);   // 16B-aligned (row stride 16KB)
      x0 = v.x; x1 = v.y; x2 = v.z; x3 = v.w;
    } else {
      x0 = (j + 0 < FAN_IN) ? ar[j + 0] : ((j + 0 == FAN_IN) ? 1.0f : 0.0f);
      x1 = (j + 1 < FAN_IN) ? ar[j + 1] : ((j + 1 == FAN_IN) ? 1.0f : 0.0f);
      x2 = (j + 2 < FAN_IN) ? ar[j + 2] : ((j + 2 == FAN_IN) ? 1.0f : 0.0f);
      x3 = (j + 3 < FAN_IN) ? ar[j + 3] : ((j + 3 == FAN_IN) ? 1.0f : 0.0f);
    }
    ushort4 o;
    o.x = f2bf(x0); o.y = f2bf(x1); o.z = f2bf(x2); o.w = f2bf(x3);
    *(ushort4*)(er + j) = o;   // 8B store, aligned (row stride 8320B, j mult of 4)
  }
}

// ---- Kernel 2 (R2): Wv[i][j] = bf16(W[hash_idx[i][j]]) via LDS-resident table.
// 1024 blocks x 512 threads; block handles 4 rows. Two phases: LDS holds
// bf16(W[h*32768 .. h*32768+32768)) (64 KB); indices live in registers.
__global__ __launch_bounds__(512) void build_wv(
    const int* __restrict__ hidx, const float* __restrict__ W,
    unsigned short* __restrict__ Wv) {
  __shared__ unsigned short wl[32768];   // 64 KB: half of W as bf16
  const int t  = threadIdx.x;
  const int r0 = blockIdx.x * 4;

  // Load this block's indices into registers (fully coalesced: 4B/lane-consecutive)
  int          idx[4][9];
  unsigned short res[4][9];
#pragma unroll
  for (int row = 0; row < 4; row++) {
    const int* hr = hidx + (size_t)(r0 + row) * KD;
#pragma unroll
    for (int i = 0; i < 9; i++) {
      const int j = i * 512 + t;
      idx[row][i] = (j < KD) ? hr[j] : 0;
      res[row][i] = 0;
    }
  }

  for (int h = 0; h < 2; h++) {
    __syncthreads();   // protect phase-0 reads before phase-1 refill
    // Fill LDS: 32768 floats -> bf16. float4 loads, ushort4 (8B) LDS writes
    // (lane byte-stride 8 -> 2-way bank alias, free per m136).
    const float4* Wb = (const float4*)(W + h * 32768);
#pragma unroll
    for (int i = 0; i < 16; i++) {
      const int f4 = i * 512 + t;
      const float4 v = Wb[f4];
      ushort4 o;
      o.x = f2bf(v.x); o.y = f2bf(v.y); o.z = f2bf(v.z); o.w = f2bf(v.w);
      *(ushort4*)&wl[f4 * 4] = o;
    }
    __syncthreads();
    const int lo = h << 15;
#pragma unroll
    for (int row = 0; row < 4; row++)
#pragma unroll
      for (int i = 0; i < 9; i++) {
        const int v = idx[row][i];
        if ((v & 32768) == lo)            // index falls in resident half
          res[row][i] = wl[v & 32767];    // random ds_read_u16
      }
  }

  // Store results + zero the KD..KP-1 pad columns
#pragma unroll
  for (int row = 0; row < 4; row++) {
    unsigned short* wr = Wv + (size_t)(r0 + row) * KP;
#pragma unroll
    for (int i = 0; i < 9; i++) {
      const int j = i * 512 + t;
      if (j < KD) wr[j] = res[row][i];
    }
    if (t < KP - KD) wr[KD + t] = 0;
  }
}

// ---- Kernel 3 (R3): C[M][N] = A[M][KP] * Bm[N][KP]^T  (bf16 in, fp32 out)
// 128x128 block tile, BK=64, 4 waves in 2x2, each wave 64x64 = 4x4 MFMA tiles.
// 32 MFMA + 16 ds_read_b128 + 8 global_load_lds per thread per barrier-pair.
__global__ __launch_bounds__(256) void gemm_bt(
    const unsigned short* __restrict__ A, const unsigned short* __restrict__ Bm,
    float* __restrict__ C, int M, int N) {
  __shared__ __align__(16) unsigned short As[BM * BK];   // 16 KB, row-major [128][64]
  __shared__ __align__(16) unsigned short Bs[BN * BK];   // 16 KB

  const int tid  = threadIdx.x;
  const int lane = tid & 63;
  const int wave = tid >> 6;
  const int bm = blockIdx.y * BM;
  const int bn = blockIdx.x * BN;
  const int wm = (wave >> 1) * 64;
  const int wn = (wave & 1) * 64;
  const int q  = lane >> 4;        // k-quad for MFMA operand layout
  const int r  = lane & 15;        // m/n index within 16
  const int srow = lane >> 3;      // staging: 8 rows per wave-load (128B/row)
  const int scol = (lane & 7) * 8; // staging: 8 bf16 (16B) per lane

  floatx4 acc[4][4] = {};

  for (int k0 = 0; k0 < KP; k0 += BK) {
    // stage: each wave DMAs 4x8 rows of A and of B (128B/row = 8 lanes/row)
#pragma unroll
    for (int l = 0; l < 4; l++) {
      const int trow = wave * 32 + l * 8;
      async16(A  + (size_t)(bm + trow + srow) * KP + k0 + scol, &As[trow * BK]);
      async16(Bm + (size_t)(bn + trow + srow) * KP + k0 + scol, &Bs[trow * BK]);
    }
    __syncthreads();   // emits s_waitcnt vmcnt(0) -> DMA complete for all waves

#pragma unroll
    for (int kk = 0; kk < 2; kk++) {
      short8 af[4], bf[4];
#pragma unroll
      for (int t = 0; t < 4; t++) {
        // A-operand layout: A[m = lane&15][k = q*8 + j] (16B contig -> ds_read_b128)
        af[t] = *(const short8*)&As[(wm + t * 16 + r) * BK + kk * 32 + q * 8];
        bf[t] = *(const short8*)&Bs[(wn + t * 16 + r) * BK + kk * 32 + q * 8];
      }
#pragma unroll
      for (int mt = 0; mt < 4; mt++)
#pragma unroll
        for (int nt = 0; nt < 4; nt++)
          acc[mt][nt] = __builtin_amdgcn_mfma_f32_16x16x32_bf16(
              af[mt], bf[nt], acc[mt][nt], 0, 0, 0);
    }
    __syncthreads();   // protect LDS from next iteration's staging
  }

  // C/D layout (verified m89/m91): col = lane&15, row = q*4 + reg
#pragma unroll
  for (int mt = 0; mt < 4; mt++)
#pragma unroll
    for (int nt = 0; nt < 4; nt++) {
      const int row0 = bm + wm + mt * 16 + q * 4;
      const int col  = bn + wn + nt * 16 + r;
#pragma unroll
      for (int i = 0; i < 4; i++)
        C[(size_t)(row0 + i) * N + col] = acc[mt][nt][i];
    }
}

extern "C" void kernel_launch(void* const* d_in, const int* in_sizes, int n_in,
                              void* d_out, int out_size, void* d_ws, size_t ws_size,
                              hipStream_t stream) {
  const float* a    = (const float*)d_in[0];   // [4096, 4096] fp32
  const int*   hidx = (const int*)d_in[1];     // [4096, 4097] int32
  const float* W    = (const float*)d_in[2];   // [65536] fp32
  float*       out  = (float*)d_out;           // [4096, 4096] fp32

  // workspace layout: A_ext bf16 [B_DIM][KP] | Wv bf16 [FAN_OUT][KP]  (68.2 MB)
  unsigned short* Ae = (unsigned short*)d_ws;
  unsigned short* Wv = Ae + (size_t)B_DIM * KP;

  build_aext<<<B_DIM, 256, 0, stream>>>(a, Ae);
  build_wv<<<FAN_OUT / 4, 512, 0, stream>>>(hidx, W, Wv);
  gemm_bt<<<dim3(FAN_OUT / BN, B_DIM / BM), 256, 0, stream>>>(Ae, Wv, out, B_DIM, FAN_OUT);
}